// Round 5
// baseline (671.465 us; speedup 1.0000x reference)
//
#include <hip/hip_runtime.h>
#include <hip/hip_cooperative_groups.h>

namespace cg = cooperative_groups;

#define N_Q   16384
#define C_DIM 128
#define S_CAM 6
#define M_VAL 1400   // 28*50
#define D_Z   8
#define HF    28
#define WF    50
#define QPB   8      // queries per block (phase 2)
#define NG    (N_Q/QPB)          // 2048 query groups
#define VROWG 525                // 8400/16 row groups (phase 1)

__device__ __forceinline__ float bflo(unsigned u){ return __uint_as_float(u << 16); }
__device__ __forceinline__ float bfhi(unsigned u){ return __uint_as_float(u & 0xffff0000u); }

union SharedU {
  float tile[16][C_DIM];                   // phase 1 staging (8 KB)
  struct {                                 // phase 2 (~16.6 KB)
    float  qs[QPB][C_DIM];                 // q staging, reused as slots
    float  offs[QPB][64];
    float  attns[QPB][32];
    float  logits[QPB][32];
    float4 swt [8][33];                    // [p][qi*4+h], +1 row pad: conflict-free
    int4   sidx[8][33];
    int    activ[QPB][S_CAM];
    float  cinv[QPB];
  } p2;
};

__device__ __forceinline__ bool mask_any(const unsigned char* __restrict__ mask,
                                         int mflag, size_t mbase){
  if(mflag==0){
    int any=0;
    #pragma unroll
    for(int d=0;d<D_Z;d++) any |= mask[mbase+d];
    return any!=0;
  } else if(mflag==1){
    const int* mp = (const int*)mask;  int any=0;
    #pragma unroll
    for(int d=0;d<D_Z;d++) any |= mp[mbase+d];
    return any!=0;
  } else {
    const long long* mp = (const long long*)mask;  long long any=0;
    #pragma unroll
    for(int d=0;d<D_Z;d++) any |= mp[mbase+d];
    return any!=0;
  }
}

// ---------------------------------------------------------------------------
// Single cooperative kernel:
//   phase 1: vproj = value @ Wv + bv  -> bf16 workspace  (+ mask-format sniff)
//   grid.sync()
//   phase 2: q-proj -> softmax -> bilinear gather (bf16) -> masked avg
//            -> out-proj + residual
// ---------------------------------------------------------------------------
__global__ __launch_bounds__(256, 8)
void bev_coop_kernel(const float* __restrict__ value,
                     const float* __restrict__ Wv,
                     const float* __restrict__ bv,
                     unsigned short* __restrict__ vb16,
                     const unsigned char* __restrict__ mask,
                     int* __restrict__ flag,
                     const float* __restrict__ query,
                     const float* __restrict__ query_pos,
                     const float* __restrict__ Wo, const float* __restrict__ bo,
                     const float* __restrict__ Wa, const float* __restrict__ ba,
                     const float* __restrict__ ref,
                     const float* __restrict__ Wout,
                     const float* __restrict__ bout,
                     float* __restrict__ out){
  __shared__ SharedU sh;
  __shared__ int s_cntA, s_cntB;
  const int tid = threadIdx.x;

  // ================= phase 1: value projection =================
  {
    const int col = tid & 127;
    const int rh  = tid >> 7;                  // row half: 0/1 -> rows rh*8..rh*8+7
    for(int g = blockIdx.x; g < VROWG; g += gridDim.x){
      const int r0 = g*16;
      {
        const float4* src = (const float4*)(value + (size_t)r0*C_DIM);
        float4* dst = (float4*)&sh.tile[0][0];
        dst[tid]       = src[tid];
        dst[tid + 256] = src[tid + 256];
      }
      __syncthreads();
      float acc[8];
      const float bias = bv[col];
      #pragma unroll
      for(int r=0;r<8;r++) acc[r]=bias;
      for(int k=0;k<C_DIM;k++){
        const float w = Wv[k*C_DIM + col];
        #pragma unroll
        for(int r=0;r<8;r++) acc[r] += sh.tile[rh*8+r][k]*w;
      }
      #pragma unroll
      for(int r=0;r<8;r++){
        const float a = acc[r];
        unsigned u = __float_as_uint(a);
        u += 0x7fff + ((u >> 16) & 1);         // round-to-nearest-even bf16
        vb16[(size_t)(r0+rh*8+r)*C_DIM + col] = (unsigned short)(u >> 16);
      }
      __syncthreads();
    }
    if(blockIdx.x==0){                         // mask-format sniff
      if(tid==0){ s_cntA=0; s_cntB=0; }
      __syncthreads();
      int a=0, b=0;
      for(int i=tid;i<1024;i+=256){
        const unsigned char v = mask[i];
        if(((i&3)!=0) && v) a=1;
        if(((i&7)==4) && v) b=1;
      }
      if(a) atomicOr(&s_cntA,1);
      if(b) atomicOr(&s_cntB,1);
      __syncthreads();
      if(tid==0) flag[0] = s_cntA ? 0 : (s_cntB ? 1 : 2);
    }
  }

  __threadfence();
  cg::this_grid().sync();

  // ================= phase 2: fused deformable attention =================
  const int mflag = *(volatile const int*)flag;
  const int qi  = tid >> 5;
  const int l   = tid & 31;
  const int gh  = l >> 3;                      // gather: head
  const int gch = gh*32 + (l&7)*4;             // gather: first channel of 4
  const int pp  = l >> 2;                      // precompute: point
  const int phh = l & 3;                       // precompute: head

  for(int g = blockIdx.x; g < NG; g += gridDim.x){
    const int n0 = g*QPB;
    // ---- q = query + query_pos ----
    {
      const float4* qa = (const float4*)(query     + (size_t)n0*C_DIM);
      const float4* qb = (const float4*)(query_pos + (size_t)n0*C_DIM);
      float4 A = qa[tid], B = qb[tid];
      ((float4*)&sh.p2.qs[0][0])[tid] = make_float4(A.x+B.x, A.y+B.y, A.z+B.z, A.w+B.w);
    }
    __syncthreads();
    // ---- offset/attn projections: (qi, col) ----
    {
      const int col = l;
      float acc0 = bo[col], acc1 = bo[col+32], acc2 = ba[col];
      for(int k=0;k<C_DIM;k++){
        const float qv = sh.p2.qs[qi][k];
        acc0 += qv * Wo[k*64 + col];
        acc1 += qv * Wo[k*64 + col + 32];
        acc2 += qv * Wa[k*32 + col];
      }
      sh.p2.offs[qi][col]    = acc0;
      sh.p2.offs[qi][col+32] = acc1;
      sh.p2.logits[qi][col]  = acc2;
    }
    if(tid < QPB*S_CAM){
      const int q2 = tid / S_CAM, s = tid % S_CAM;
      sh.p2.activ[q2][s] = mask_any(mask, mflag, ((size_t)s*N_Q + (n0+q2))*D_Z) ? 1 : 0;
    }
    __syncthreads();
    if(tid < 32){                              // softmax over P=8: (q2, h)
      const int q2 = tid >> 2, h = tid & 3;
      const float* L = &sh.p2.logits[q2][h*8];
      float mx = L[0];
      #pragma unroll
      for(int p=1;p<8;p++) mx = fmaxf(mx, L[p]);
      float e[8], ssum = 0.f;
      #pragma unroll
      for(int p=0;p<8;p++){ e[p] = __expf(L[p]-mx); ssum += e[p]; }
      const float inv = 1.f/ssum;
      #pragma unroll
      for(int p=0;p<8;p++) sh.p2.attns[q2][h*8+p] = e[p]*inv;
    } else if(tid >= 256-QPB){
      const int q2 = tid - (256-QPB);
      int c = 0;
      #pragma unroll
      for(int s=0;s<S_CAM;s++) c += sh.p2.activ[q2][s];
      sh.p2.cinv[q2] = 1.f / fmaxf((float)c, 1.f);
    }
    __syncthreads();

    // ---- per-camera precompute + gather ----
    float ax=0.f, ay=0.f, az=0.f, aw=0.f;
    for(int s=0;s<S_CAM;s++){
      {   // one lane per (qi, p, h)
        const float2 r2 = ((const float2*)(ref + ((size_t)s*N_Q + (n0+qi))*D_Z*2))[pp];
        const float x = (r2.x + sh.p2.offs[qi][phh*16+pp*2+0]*(1.0f/(float)WF))*(float)WF - 0.5f;
        const float y = (r2.y + sh.p2.offs[qi][phh*16+pp*2+1]*(1.0f/(float)HF))*(float)HF - 0.5f;
        const float x0f = floorf(x), y0f = floorf(y);
        const float fx = x - x0f,    fy = y - y0f;
        const int x0 = (int)x0f, y0 = (int)y0f;
        const int x1 = x0+1,     y1 = y0+1;
        const float at = sh.p2.activ[qi][s] ? sh.p2.attns[qi][phh*8+pp] : 0.f;
        const float wx0 = (x0>=0 && x0<WF) ? (1.f-fx) : 0.f;
        const float wx1 = (x1>=0 && x1<WF) ? fx       : 0.f;
        const float wy0 = ((y0>=0 && y0<HF) ? (1.f-fy) : 0.f) * at;
        const float wy1 = ((y1>=0 && y1<HF) ? fy       : 0.f) * at;
        const int x0c = min(max(x0,0), WF-1), x1c = min(max(x1,0), WF-1);
        const int y0c = min(max(y0,0), HF-1), y1c = min(max(y1,0), HF-1);
        sh.p2.swt [pp][qi*4+phh] = make_float4(wx0*wy0, wx1*wy0, wx0*wy1, wx1*wy1);
        sh.p2.sidx[pp][qi*4+phh] = make_int4((y0c*WF+x0c)*C_DIM, (y0c*WF+x1c)*C_DIM,
                                             (y1c*WF+x0c)*C_DIM, (y1c*WF+x1c)*C_DIM);
      }
      __syncthreads();
      {   // gather: (qi, h, c4) -> 4 channels as 2 bf16-pairs
        const unsigned short* vb = vb16 + (size_t)s*M_VAL*C_DIM + gch;
        #pragma unroll
        for(int p=0;p<8;p++){
          const int4   id = sh.p2.sidx[p][qi*4+gh];
          const float4 w  = sh.p2.swt [p][qi*4+gh];
          const uint2 a0 = *(const uint2*)(vb + id.x);
          const uint2 a1 = *(const uint2*)(vb + id.y);
          const uint2 a2 = *(const uint2*)(vb + id.z);
          const uint2 a3 = *(const uint2*)(vb + id.w);
          ax += w.x*bflo(a0.x) + w.y*bflo(a1.x) + w.z*bflo(a2.x) + w.w*bflo(a3.x);
          ay += w.x*bfhi(a0.x) + w.y*bfhi(a1.x) + w.z*bfhi(a2.x) + w.w*bfhi(a3.x);
          az += w.x*bflo(a0.y) + w.y*bflo(a1.y) + w.z*bflo(a2.y) + w.w*bflo(a3.y);
          aw += w.x*bfhi(a0.y) + w.y*bfhi(a1.y) + w.z*bfhi(a2.y) + w.w*bfhi(a3.y);
        }
      }
      __syncthreads();
    }

    // ---- slots (reuse qs) -> out-proj + residual ----
    {
      const float inv = sh.p2.cinv[qi];
      *(float4*)&sh.p2.qs[qi][gch] = make_float4(ax*inv, ay*inv, az*inv, aw*inv);
    }
    __syncthreads();
    {
      const int c4 = l;                        // cols 4*c4 .. 4*c4+3
      const int n  = n0 + qi;
      const float4 b4 = *(const float4*)&bout[c4*4];
      const float4 r4 = *(const float4*)&query[(size_t)n*C_DIM + c4*4];
      float ox = b4.x + r4.x, oy = b4.y + r4.y, oz = b4.z + r4.z, ow = b4.w + r4.w;
      for(int k=0;k<C_DIM;k++){
        const float sv = sh.p2.qs[qi][k];
        const float4 w = *(const float4*)&Wout[(size_t)k*C_DIM + c4*4];
        ox += sv*w.x; oy += sv*w.y; oz += sv*w.z; ow += sv*w.w;
      }
      *(float4*)&out[(size_t)n*C_DIM + c4*4] = make_float4(ox, oy, oz, ow);
    }
    __syncthreads();                           // protect qs before next group
  }
}

extern "C" void kernel_launch(void* const* d_in, const int* in_sizes, int n_in,
                              void* d_out, int out_size, void* d_ws, size_t ws_size,
                              hipStream_t stream){
  const float* value     = (const float*)d_in[2];
  const float* Wv   = (const float*)d_in[5];
  const float* bv   = (const float*)d_in[6];
  const float* query     = (const float*)d_in[0];
  const float* query_pos = (const float*)d_in[1];
  const float* Wo   = (const float*)d_in[7];
  const float* bo   = (const float*)d_in[8];
  const float* Wa   = (const float*)d_in[9];
  const float* ba   = (const float*)d_in[10];
  const float* ref  = (const float*)d_in[3];
  const unsigned char* mask = (const unsigned char*)d_in[4];
  const float* Wout = (const float*)d_in[11];
  const float* bout = (const float*)d_in[12];
  float* out = (float*)d_out;

  int* flag = (int*)d_ws;
  unsigned short* vb16 = (unsigned short*)((char*)d_ws + 64);

  int nb = 0;
  int grid = 1792;                             // safe default: 7 blocks/CU
  if(hipOccupancyMaxActiveBlocksPerMultiprocessor(&nb, (const void*)bev_coop_kernel,
                                                  256, 0) == hipSuccess && nb > 0){
    long cap = (long)nb * 256;
    grid = (int)(cap < 2048 ? cap : 2048);
  }

  void* kargs[] = {
    (void*)&value, (void*)&Wv, (void*)&bv, (void*)&vb16, (void*)&mask, (void*)&flag,
    (void*)&query, (void*)&query_pos, (void*)&Wo, (void*)&bo, (void*)&Wa, (void*)&ba,
    (void*)&ref, (void*)&Wout, (void*)&bout, (void*)&out
  };
  hipLaunchCooperativeKernel((void*)bev_coop_kernel, dim3(grid), dim3(256),
                             kargs, 0, stream);
}